// Round 15
// baseline (655.878 us; speedup 1.0000x reference)
//
#include <hip/hip_runtime.h>
#include <cstdint>
#include <cstddef>

#define DEVI __device__ __forceinline__

typedef __bf16 bf16x8 __attribute__((ext_vector_type(8)));
typedef float  floatx4 __attribute__((ext_vector_type(4)));

constexpr int NHEAD = 6;
constexpr int CLF = 64, CHF = 192;
constexpr int IMG = 256;
constexpr int HW  = IMG * IMG;

// ---- steady-state LDS map (head loop). O-matmul in epilogue: no WO region,
// no 48-reg f32 accumulator. 50.2KB -> 3 blocks/CU; ~136-160 regs -> the HW
// can grant 3 waves/SIMD WITHOUT a forced launch bound (R9/R14 lesson:
// forcing min_waves>=3 always induces scratch spill on this kernel). ----
constexpr int OFF_WKV = 0;       // 24576
constexpr int OFF_K   = 24576;   //  8192 -> 32768
constexpr int OFF_VT  = 32768;   //  4096 -> 36864
constexpr int OFF_PW  = 36864;   //  9216 -> 46080
constexpr int OFF_RPB = 46080;   //  2784 -> 48864
constexpr int OFF_EPO = 24576;   // epilogue O staging, pitch 200
constexpr int SMEM_BYTES = 50176;  // <= 53248 -> 3 blocks/CU (159744 <= 163840)
constexpr int P_PW = 72;

// ---- load-phase layout (time-disjoint, dead after fragment pull) ----
constexpr int LOFF_LF  = 25600;  // lf [64][72] after hf [64][200] @0
constexpr int LOFF_RED = 34816;  // stats 4KB
constexpr int P_HFL = 200, P_LFL = 72;
constexpr int P_WQ = 72;         // WqT phase [192][72] @0 = 27648

DEVI unsigned short f2b(float f) {  // fp32 -> bf16 RNE (manual, known-good)
  unsigned u = __float_as_uint(f);
  u += 0x7fffu + ((u >> 16) & 1u);
  return (unsigned short)(u >> 16);
}
DEVI float b2f(unsigned short s) { return __uint_as_float(((unsigned)s) << 16); }

DEVI floatx4 mfma_bf16(bf16x8 a, bf16x8 b, floatx4 c) {
  return __builtin_amdgcn_mfma_f32_16x16x32_bf16(a, b, c, 0, 0, 0);
}

DEVI int swz8(int row, int off) { return off ^ ((row & 7) << 3); }

// ---- prep: W[k][n] fp32 -> W^T[n][k] bf16 into workspace (RNE) ----
__global__ void wca_prep(const float* __restrict__ Wq, const float* __restrict__ Wk,
                         const float* __restrict__ Wv, const float* __restrict__ Wo,
                         unsigned short* __restrict__ wT) {
  int i = blockIdx.x * 256 + threadIdx.x;  // grid covers exactly 122880
  if (i < 12288) {                         // WqT: 192 x 64
    int n = i >> 6, k = i & 63;
    wT[i] = f2b(Wq[k * 192 + n]);
  } else if (i < 49152) {                  // WkT: 192 x 192
    int j = i - 12288, n = j / 192, k = j - n * 192;
    wT[i] = f2b(Wk[k * 192 + n]);
  } else if (i < 86016) {                  // WvT
    int j = i - 49152, n = j / 192, k = j - n * 192;
    wT[i] = f2b(Wv[k * 192 + n]);
  } else {                                 // WoT
    int j = i - 86016, n = j / 192, k = j - n * 192;
    wT[i] = f2b(Wo[k * 192 + n]);
  }
}

__global__ __launch_bounds__(256, 2) void wca_main(
    const float* __restrict__ ylf, const float* __restrict__ yhf,
    const float* __restrict__ glf, const float* __restrict__ blf,
    const float* __restrict__ ghf, const float* __restrict__ bhf,
    const float* __restrict__ bq,  const float* __restrict__ bk,
    const float* __restrict__ bv,  const float* __restrict__ bo,
    const float* __restrict__ rpb, const unsigned short* __restrict__ wT,
    float* __restrict__ out) {
  __shared__ __align__(16) char smem[SMEM_BYTES];
  unsigned short* s_wkv = (unsigned short*)(smem + OFF_WKV);
  unsigned short* s_k   = (unsigned short*)(smem + OFF_K);
  unsigned short* s_vt  = (unsigned short*)(smem + OFF_VT);
  unsigned short* s_rpb = (unsigned short*)(smem + OFF_RPB);
  // load-phase views
  unsigned short* s_hfL = (unsigned short*)(smem);
  unsigned short* s_lfL = (unsigned short*)(smem + LOFF_LF);
  float* s_red = (float*)(smem + LOFF_RED);
  // WqT-phase / epilogue views
  unsigned short* s_wq  = (unsigned short*)(smem);            // [192][72]
  unsigned short* s_ep  = (unsigned short*)(smem);            // WoT third [64][192] swz8
  unsigned short* s_os  = (unsigned short*)(smem + OFF_EPO);  // O staging [64][200]

  const int tid  = threadIdx.x;
  const int lane = tid & 63;
  const int wv   = tid >> 6;     // wave 0..3
  const int quad = lane >> 4;
  const int l16  = lane & 15;
  unsigned short* s_pw = (unsigned short*)(smem + OFF_PW) + wv * 16 * P_PW;  // [16][72]

  // XCD-pair swizzle: XCD x owns contiguous windows [x*512, +512) so
  // wx-adjacent windows (sharing every 64B HBM line) hit the same L2.
  const int g   = blockIdx.x;
  const int wid = ((g & 7) << 9) | (g >> 3);   // 4096 windows, bijective
  const int b   = wid >> 10;
  const int wy  = (wid >> 5) & 31;
  const int wx  = wid & 31;
  const int h0  = wy << 3, w0 = wx << 3;

  const int t_own = tid & 63;          // token owned for load/stats
  const int cg    = tid >> 6;          // channel block owner (wave-uniform)
  const int ty    = t_own >> 3, tx = t_own & 7;

  // ---- load windows (coalesced 32B row segments) + LN stats in fp32 ----
  float lfv[16], hfv[48];
  float ls = 0.f, l2 = 0.f, hs = 0.f, h2 = 0.f;
  {
    const float* p = ylf + ((size_t)(b * CLF + cg * 16) * IMG + (h0 + ty)) * IMG + (w0 + tx);
#pragma unroll
    for (int k = 0; k < 16; k++) {
      float v = p[(size_t)k * HW];
      lfv[k] = v; ls += v; l2 += v * v;
    }
  }
  {
    const float* p = yhf + ((size_t)(b * CHF + cg * 48) * IMG + (h0 + ty)) * IMG + (w0 + tx);
#pragma unroll
    for (int k = 0; k < 48; k++) {
      float v = p[(size_t)k * HW];
      hfv[k] = v; hs += v; h2 += v * v;
    }
  }
  s_red[0 * 256 + (cg << 6) + t_own] = ls;
  s_red[1 * 256 + (cg << 6) + t_own] = l2;
  s_red[2 * 256 + (cg << 6) + t_own] = hs;
  s_red[3 * 256 + (cg << 6) + t_own] = h2;
  __syncthreads();  // B1
  float su = 0.f, sq = 0.f, hu = 0.f, hq = 0.f;
#pragma unroll
  for (int gg = 0; gg < 4; gg++) {
    su += s_red[0 * 256 + (gg << 6) + t_own];
    sq += s_red[1 * 256 + (gg << 6) + t_own];
    hu += s_red[2 * 256 + (gg << 6) + t_own];
    hq += s_red[3 * 256 + (gg << 6) + t_own];
  }
  const float mu_lf = su * (1.f / 64.f);
  const float rs_lf = rsqrtf(sq * (1.f / 64.f) - mu_lf * mu_lf + 1e-5f);
  const float mu_hf = hu * (1.f / 192.f);
  const float rs_hf = rsqrtf(hq * (1.f / 192.f) - mu_hf * mu_hf + 1e-5f);

  // normalize + packed u64 bf16 stores (manual RNE pack — known-good)
#pragma unroll
  for (int j = 0; j < 4; j++) {
    uint64_t w = 0;
#pragma unroll
    for (int m = 0; m < 4; m++) {
      int c = cg * 16 + j * 4 + m;
      float v = (lfv[j * 4 + m] - mu_lf) * rs_lf * glf[c] + blf[c];
      w |= (uint64_t)f2b(v) << (16 * m);
    }
    *(uint64_t*)(s_lfL + t_own * P_LFL + cg * 16 + j * 4) = w;
  }
#pragma unroll
  for (int j = 0; j < 12; j++) {
    uint64_t w = 0;
#pragma unroll
    for (int m = 0; m < 4; m++) {
      int c = cg * 48 + j * 4 + m;
      float v = (hfv[j * 4 + m] - mu_hf) * rs_hf * ghf[c] + bhf[c];
      w |= (uint64_t)f2b(v) << (16 * m);
    }
    *(uint64_t*)(s_hfL + t_own * P_HFL + cg * 48 + j * 4) = w;
  }
  __syncthreads();  // B2: staging visible to all waves

  // ---- pull this wave's A-fragments into REGISTERS (own 16 rows only) ----
  const int myrow = wv * 16 + l16;
  bf16x8 lfr0 = *(const bf16x8*)(s_lfL + myrow * P_LFL + quad * 8);
  bf16x8 lfr1 = *(const bf16x8*)(s_lfL + myrow * P_LFL + 32 + quad * 8);
  bf16x8 hfr[6];
#pragma unroll
  for (int ks = 0; ks < 6; ks++)
    hfr[ks] = *(const bf16x8*)(s_hfL + myrow * P_HFL + ks * 32 + quad * 8);
  __syncthreads();  // B2b: frags in regs; whole arena reusable

  const unsigned short* wqT = wT;           // [192][64]
  const unsigned short* wkT = wT + 12288;   // [192][192]
  const unsigned short* wvT = wT + 49152;
  const unsigned short* woT = wT + 86016;

  // ---- stage WqT-all (contiguous 16B pieces, no gathers) + rpb bf16 table ----
#pragma unroll
  for (int i = 0; i < 6; i++) {
    int p = i * 256 + tid;            // 1536 pieces (192 rows x 8)
    int n = p >> 3, sub = p & 7;
    *(uint4*)(s_wq + n * P_WQ + sub * 8) = *(const uint4*)(wqT + n * 64 + sub * 8);
  }
  for (int i = tid; i < 225 * NHEAD; i += 256) s_rpb[i] = f2b(rpb[i]);
  __syncthreads();  // B3: WqT + rpb staged

  const int rowbase = wv * 16 + quad * 4;   // C-layout row base for this lane

  // ---- Q for ALL heads upfront; frags via wave-private PW round trip ----
  bf16x8 aq[NHEAD];
#pragma unroll
  for (int h = 0; h < NHEAD; h++) {
#pragma unroll
    for (int nt = 0; nt < 2; nt++) {
      const int n = h * 32 + nt * 16 + l16;
      floatx4 acc = {0.f, 0.f, 0.f, 0.f};
      acc = mfma_bf16(lfr0, *(const bf16x8*)(s_wq + n * P_WQ + quad * 8), acc);
      acc = mfma_bf16(lfr1, *(const bf16x8*)(s_wq + n * P_WQ + 32 + quad * 8), acc);
      const float bqv = bq[n];
#pragma unroll
      for (int r = 0; r < 4; r++)
        s_pw[(quad * 4 + r) * P_PW + nt * 16 + l16] = f2b(acc[r] + bqv);
    }
    aq[h] = *(const bf16x8*)(s_pw + l16 * P_PW + quad * 8);  // same-wave, in-order DS
  }
  __syncthreads();  // B4: all waves done reading WqT region

  // shared staging of the per-head WkT/WvT slices (contiguous in wT; swizzled dst)
  auto stageKV = [&](int h) {
    const unsigned short* sk = wkT + h * 6144;   // 32 rows x 192
    const unsigned short* sv = wvT + h * 6144;
#pragma unroll
    for (int i = 0; i < 3; i++) {
      int p = i * 256 + tid;          // 768 pieces of 16B per matrix
      int nl = p / 24, sub = p - nl * 24;
      *(uint4*)(s_wkv + nl * 192 + swz8(nl, sub * 8)) =
          *(const uint4*)(sk + nl * 192 + sub * 8);
      *(uint4*)(s_wkv + (32 + nl) * 192 + swz8(32 + nl, sub * 8)) =
          *(const uint4*)(sv + nl * 192 + sub * 8);
    }
  };

  stageKV(0);
  __syncthreads();  // S0: KV(0) staged

  const floatx4 zero = {0.f, 0.f, 0.f, 0.f};
  bf16x8 aob[NHEAD];  // per-head AO fragments (A-layout, own 16 rows) — 24 VGPR

#pragma unroll
  for (int h = 0; h < NHEAD; h++) {
    // ---- K_h -> s_k (A from hfr regs; 2 parallel 3-chains halve MFMA latency) ----
#pragma unroll
    for (int nt = 0; nt < 2; nt++) {
      const int n = h * 32 + nt * 16 + l16;
      const int nl = nt * 16 + l16;
      floatx4 a0 = zero, a1 = zero;
#pragma unroll
      for (int ks = 0; ks < 3; ks++) {
        a0 = mfma_bf16(hfr[ks],
            *(const bf16x8*)(s_wkv + nl * 192 + swz8(nl, ks * 32 + quad * 8)), a0);
        a1 = mfma_bf16(hfr[ks + 3],
            *(const bf16x8*)(s_wkv + nl * 192 + swz8(nl, (ks + 3) * 32 + quad * 8)), a1);
      }
      floatx4 acc = a0 + a1;
      const float bkv = bk[n];
#pragma unroll
      for (int r = 0; r < 4; r++)
        s_k[(rowbase + r) * 64 + swz8(rowbase + r, nt * 16 + l16)] = f2b(acc[r] + bkv);
    }
    // ---- V_h -> s_vt (transposed store, swizzled; split chains) ----
#pragma unroll
    for (int nt = 0; nt < 2; nt++) {
      const int n = h * 32 + nt * 16 + l16;
      const int nl = nt * 16 + l16;
      floatx4 a0 = zero, a1 = zero;
#pragma unroll
      for (int ks = 0; ks < 3; ks++) {
        a0 = mfma_bf16(hfr[ks],
            *(const bf16x8*)(s_wkv + (32 + nl) * 192 + swz8(32 + nl, ks * 32 + quad * 8)), a0);
        a1 = mfma_bf16(hfr[ks + 3],
            *(const bf16x8*)(s_wkv + (32 + nl) * 192 + swz8(32 + nl, (ks + 3) * 32 + quad * 8)), a1);
      }
      floatx4 acc = a0 + a1;
      const float bvv = bv[n];
#pragma unroll
      for (int r = 0; r < 4; r++)
        s_vt[nl * 64 + swz8(nl, rowbase + r)] = f2b(acc[r] + bvv);
    }
    __syncthreads();  // A(h): s_k/s_vt visible; WKV slice dead for all waves

    // ---- stage KV(h+1); loads retire under the attn math below ----
    if (h + 1 < NHEAD) stageKV(h + 1);

    // ---- S = Q K^T * scale + rpb (wave owns query rows wv*16..+15) ----
    float sv[4][4];
#pragma unroll
    for (int ct = 0; ct < 4; ct++) {
      const int kr = ct * 16 + l16;
      bf16x8 kb = *(const bf16x8*)(s_k + kr * 64 + swz8(kr, quad * 8));
      floatx4 acc = zero;
      acc = mfma_bf16(aq[h], kb, acc);
#pragma unroll
      for (int r = 0; r < 4; r++) {
        int row = rowbase + r, col = kr;
        int dy = (row >> 3) - (col >> 3) + 7;
        int dx = (row & 7) - (col & 7) + 7;
        sv[ct][r] = acc[r] * 0.17677669529663688f + b2f(s_rpb[(dy * 15 + dx) * NHEAD + h]);
      }
    }
    // ---- softmax over 64 keys, NO max-subtraction: scores bounded (LN inputs,
    // weight scale 0.02 => |S| <~ 1); exp2 cannot overflow, denom >= 64*exp2(-1). ----
#pragma unroll
    for (int r = 0; r < 4; r++) {
      const float L2E = 1.4426950408889634f;
      float e0 = exp2f(sv[0][r] * L2E);
      float e1 = exp2f(sv[1][r] * L2E);
      float e2 = exp2f(sv[2][r] * L2E);
      float e3 = exp2f(sv[3][r] * L2E);
      float s = e0 + e1 + e2 + e3;
      s += __shfl_xor(s, 1);
      s += __shfl_xor(s, 2);
      s += __shfl_xor(s, 4);
      s += __shfl_xor(s, 8);
      float inv = 1.f / s;
      sv[0][r] = e0 * inv; sv[1][r] = e1 * inv; sv[2][r] = e2 * inv; sv[3][r] = e3 * inv;
    }
    // ---- P -> wave-private PW (no cross-wave barrier needed) ----
#pragma unroll
    for (int ct = 0; ct < 4; ct++)
#pragma unroll
      for (int r = 0; r < 4; r++)
        s_pw[(quad * 4 + r) * P_PW + ct * 16 + l16] = f2b(sv[ct][r]);

    // ---- PV (wave-local P round trip; in-order DS) ----
    floatx4 pv0 = zero, pv1 = zero;
#pragma unroll
    for (int ks = 0; ks < 2; ks++) {
      bf16x8 pa = *(const bf16x8*)(s_pw + l16 * P_PW + ks * 32 + quad * 8);
      pv0 = mfma_bf16(pa, *(const bf16x8*)(s_vt + l16 * 64 + swz8(l16, ks * 32 + quad * 8)), pv0);
      pv1 = mfma_bf16(pa, *(const bf16x8*)(s_vt + (16 + l16) * 64 + swz8(16 + l16, ks * 32 + quad * 8)), pv1);
    }
    // stage AO_h into PW cols 0..31 and pull back as an A-fragment (24 VGPR total)
#pragma unroll
    for (int r = 0; r < 4; r++) {
      s_pw[(quad * 4 + r) * P_PW + l16]      = f2b(pv0[r]);
      s_pw[(quad * 4 + r) * P_PW + 16 + l16] = f2b(pv1[r]);
    }
    aob[h] = *(const bf16x8*)(s_pw + l16 * P_PW + quad * 8);
    __syncthreads();  // A2(h): KV(h+1) published; s_k/s_vt reads done ->
                      // next head's K/V compute may overwrite them.
  }
  // (A2(5) doubles as the epilogue entry barrier: all WKV/K/VT/PW reads done.)

  // ---- epilogue: O = AO @ Wo, WoT staged in 3 thirds into dead arena @0 ----
#pragma unroll
  for (int t = 0; t < 3; t++) {
    // stage WoT rows 64t..64t+63 ([64 outcols][192 k]) swz8 @0
#pragma unroll
    for (int i = 0; i < 6; i++) {
      int p = i * 256 + tid;
      int nl = p / 24, sub = p - nl * 24;
      *(uint4*)(s_ep + nl * 192 + swz8(nl, sub * 8)) =
          *(const uint4*)(woT + (t * 64 + nl) * 192 + sub * 8);
    }
    __syncthreads();
#pragma unroll
    for (int c4 = 0; c4 < 4; c4++) {
      const int nl = c4 * 16 + l16;
      floatx4 acc = zero;
#pragma unroll
      for (int ks = 0; ks < 6; ks++)
        acc = mfma_bf16(aob[ks],
            *(const bf16x8*)(s_ep + nl * 192 + swz8(nl, ks * 32 + quad * 8)), acc);
      const int col = t * 64 + c4 * 16 + l16;
      const float bov = bo[col];
#pragma unroll
      for (int r = 0; r < 4; r++)
        s_os[(rowbase + r) * 200 + col] = f2b(acc[r] + bov);
    }
    __syncthreads();  // WoT-third reads done; (t=2) O staging complete
  }

  // ---- coalesced float4 store; residual re-read from global (L3-warm) ----
#pragma unroll
  for (int k = 0; k < 12; k++) {
    int chunk = k * 256 + tid;       // 3072 chunks of 4 floats = 192ch x 64tok
    int c   = chunk >> 4;
    int sub = chunk & 15;
    int yy  = sub >> 1;
    int x4  = (sub & 1) << 2;
    int t0  = (yy << 3) + x4;
    size_t gidx = ((size_t)(b * CHF + c) * IMG + (h0 + yy)) * IMG + w0 + x4;
    float4 res = *(const float4*)(yhf + gidx);
    float4 v;
    v.x = b2f(s_os[(t0 + 0) * 200 + c]) + res.x;
    v.y = b2f(s_os[(t0 + 1) * 200 + c]) + res.y;
    v.z = b2f(s_os[(t0 + 2) * 200 + c]) + res.z;
    v.w = b2f(s_os[(t0 + 3) * 200 + c]) + res.w;
    *(float4*)(out + gidx) = v;
  }
}

extern "C" void kernel_launch(void* const* d_in, const int* in_sizes, int n_in,
                              void* d_out, int out_size, void* d_ws, size_t ws_size,
                              hipStream_t stream) {
  const float* ylf = (const float*)d_in[0];
  const float* yhf = (const float*)d_in[1];
  const float* glf = (const float*)d_in[2];
  const float* blf = (const float*)d_in[3];
  const float* ghf = (const float*)d_in[4];
  const float* bhf = (const float*)d_in[5];
  const float* Wq  = (const float*)d_in[6];
  const float* bq  = (const float*)d_in[7];
  const float* Wk  = (const float*)d_in[8];
  const float* bk  = (const float*)d_in[9];
  const float* Wv  = (const float*)d_in[10];
  const float* bv  = (const float*)d_in[11];
  const float* Wo  = (const float*)d_in[12];
  const float* bo  = (const float*)d_in[13];
  const float* rpb = (const float*)d_in[14];
  unsigned short* wT = (unsigned short*)d_ws;  // 122880 bf16 = 245760 B

  wca_prep<<<480, 256, 0, stream>>>(Wq, Wk, Wv, Wo, wT);
  wca_main<<<4096, 256, 0, stream>>>(ylf, yhf, glf, blf, ghf, bhf,
                                     bq, bk, bv, bo, rpb, wT, (float*)d_out);
}

// Round 16
// 626.174 us; speedup vs baseline: 1.0474x; 1.0474x over previous
//
#include <hip/hip_runtime.h>
#include <cstdint>
#include <cstddef>

#define DEVI __device__ __forceinline__

typedef __bf16 bf16x8 __attribute__((ext_vector_type(8)));
typedef float  floatx4 __attribute__((ext_vector_type(4)));

constexpr int NHEAD = 6;
constexpr int CLF = 64, CHF = 192;
constexpr int IMG = 256;
constexpr int HW  = IMG * IMG;

// ---- steady-state LDS map (head loop) ----
// WKV [64][192] swz8 | WO [192][32] swz4 | K [64][64] swz8 | VT [32][64] swz8
// PW 4 x [16][72] per-wave P/AO/Q scratch | rpb bf16 table
constexpr int OFF_WKV = 0;       // 24576
constexpr int OFF_WO  = 24576;   // 12288 -> 36864
constexpr int OFF_K   = 36864;   //  8192 -> 45056
constexpr int OFF_VT  = 45056;   //  4096 -> 49152
constexpr int OFF_PW  = 49152;   //  9216 -> 58368
constexpr int OFF_RPB = 58368;   //  2704 -> 61072
constexpr int SMEM_BYTES = 61072;  // 2 blocks/CU (<= 81920)
constexpr int P_PW = 72;

// ---- load-phase layout (time-disjoint, dead after fragment pull) ----
constexpr int LOFF_LF  = 25600;  // lf [64][72] after hf [64][200] @0
constexpr int LOFF_RED = 34816;  // stats 4KB
constexpr int P_HFL = 200, P_LFL = 72;
constexpr int P_WQ = 72;         // WqT phase [192][72] @0 = 27648

DEVI unsigned short f2b(float f) {  // fp32 -> bf16 RNE (manual, known-good)
  unsigned u = __float_as_uint(f);
  u += 0x7fffu + ((u >> 16) & 1u);
  return (unsigned short)(u >> 16);
}
DEVI float b2f(unsigned short s) { return __uint_as_float(((unsigned)s) << 16); }

DEVI floatx4 mfma_bf16(bf16x8 a, bf16x8 b, floatx4 c) {
  return __builtin_amdgcn_mfma_f32_16x16x32_bf16(a, b, c, 0, 0, 0);
}

DEVI int swz8(int row, int off) { return off ^ ((row & 7) << 3); }
DEVI int swz4(int row, int off) { return off ^ ((row & 3) << 3); }

// ---- prep: W[k][n] fp32 -> W^T[n][k] bf16 into workspace (RNE) ----
__global__ void wca_prep(const float* __restrict__ Wq, const float* __restrict__ Wk,
                         const float* __restrict__ Wv, const float* __restrict__ Wo,
                         unsigned short* __restrict__ wT) {
  int i = blockIdx.x * 256 + threadIdx.x;  // grid covers exactly 122880
  if (i < 12288) {                         // WqT: 192 x 64
    int n = i >> 6, k = i & 63;
    wT[i] = f2b(Wq[k * 192 + n]);
  } else if (i < 49152) {                  // WkT: 192 x 192
    int j = i - 12288, n = j / 192, k = j - n * 192;
    wT[i] = f2b(Wk[k * 192 + n]);
  } else if (i < 86016) {                  // WvT
    int j = i - 49152, n = j / 192, k = j - n * 192;
    wT[i] = f2b(Wv[k * 192 + n]);
  } else {                                 // WoT
    int j = i - 86016, n = j / 192, k = j - n * 192;
    wT[i] = f2b(Wo[k * 192 + n]);
  }
}

__global__ __launch_bounds__(256, 2) void wca_main(
    const float* __restrict__ ylf, const float* __restrict__ yhf,
    const float* __restrict__ glf, const float* __restrict__ blf,
    const float* __restrict__ ghf, const float* __restrict__ bhf,
    const float* __restrict__ bq,  const float* __restrict__ bk,
    const float* __restrict__ bv,  const float* __restrict__ bo,
    const float* __restrict__ rpb, const unsigned short* __restrict__ wT,
    float* __restrict__ out) {
  __shared__ __align__(16) char smem[SMEM_BYTES];
  unsigned short* s_wkv = (unsigned short*)(smem + OFF_WKV);
  unsigned short* s_wo  = (unsigned short*)(smem + OFF_WO);
  unsigned short* s_k   = (unsigned short*)(smem + OFF_K);
  unsigned short* s_vt  = (unsigned short*)(smem + OFF_VT);
  unsigned short* s_rpb = (unsigned short*)(smem + OFF_RPB);
  // load-phase views
  unsigned short* s_hfL = (unsigned short*)(smem);
  unsigned short* s_lfL = (unsigned short*)(smem + LOFF_LF);
  float* s_red = (float*)(smem + LOFF_RED);
  // WqT-phase view
  unsigned short* s_wq = (unsigned short*)(smem);

  const int tid  = threadIdx.x;
  const int lane = tid & 63;
  const int wv   = tid >> 6;     // wave 0..3
  const int quad = lane >> 4;
  const int l16  = lane & 15;
  unsigned short* s_pw = (unsigned short*)(smem + OFF_PW) + wv * 16 * P_PW;  // [16][72]

  // XCD-pair swizzle: XCD x owns contiguous windows [x*512, +512) so
  // wx-adjacent windows (sharing every 64B HBM line) hit the same L2.
  const int g   = blockIdx.x;
  const int wid = ((g & 7) << 9) | (g >> 3);   // 4096 windows, bijective
  const int b   = wid >> 10;
  const int wy  = (wid >> 5) & 31;
  const int wx  = wid & 31;
  const int h0  = wy << 3, w0 = wx << 3;

  const int t_own = tid & 63;          // token owned for load/stats
  const int cg    = tid >> 6;          // channel block owner (wave-uniform)
  const int ty    = t_own >> 3, tx = t_own & 7;

  // ---- load windows (coalesced 32B row segments) + LN stats in fp32 ----
  float lfv[16], hfv[48];
  float ls = 0.f, l2 = 0.f, hs = 0.f, h2 = 0.f;
  {
    const float* p = ylf + ((size_t)(b * CLF + cg * 16) * IMG + (h0 + ty)) * IMG + (w0 + tx);
#pragma unroll
    for (int k = 0; k < 16; k++) {
      float v = p[(size_t)k * HW];
      lfv[k] = v; ls += v; l2 += v * v;
    }
  }
  {
    const float* p = yhf + ((size_t)(b * CHF + cg * 48) * IMG + (h0 + ty)) * IMG + (w0 + tx);
#pragma unroll
    for (int k = 0; k < 48; k++) {
      float v = p[(size_t)k * HW];
      hfv[k] = v; hs += v; h2 += v * v;
    }
  }
  s_red[0 * 256 + (cg << 6) + t_own] = ls;
  s_red[1 * 256 + (cg << 6) + t_own] = l2;
  s_red[2 * 256 + (cg << 6) + t_own] = hs;
  s_red[3 * 256 + (cg << 6) + t_own] = h2;
  __syncthreads();  // B1
  float su = 0.f, sq = 0.f, hu = 0.f, hq = 0.f;
#pragma unroll
  for (int gg = 0; gg < 4; gg++) {
    su += s_red[0 * 256 + (gg << 6) + t_own];
    sq += s_red[1 * 256 + (gg << 6) + t_own];
    hu += s_red[2 * 256 + (gg << 6) + t_own];
    hq += s_red[3 * 256 + (gg << 6) + t_own];
  }
  const float mu_lf = su * (1.f / 64.f);
  const float rs_lf = rsqrtf(sq * (1.f / 64.f) - mu_lf * mu_lf + 1e-5f);
  const float mu_hf = hu * (1.f / 192.f);
  const float rs_hf = rsqrtf(hq * (1.f / 192.f) - mu_hf * mu_hf + 1e-5f);

  // normalize + packed u64 bf16 stores (manual RNE pack — known-good)
#pragma unroll
  for (int j = 0; j < 4; j++) {
    uint64_t w = 0;
#pragma unroll
    for (int m = 0; m < 4; m++) {
      int c = cg * 16 + j * 4 + m;
      float v = (lfv[j * 4 + m] - mu_lf) * rs_lf * glf[c] + blf[c];
      w |= (uint64_t)f2b(v) << (16 * m);
    }
    *(uint64_t*)(s_lfL + t_own * P_LFL + cg * 16 + j * 4) = w;
  }
#pragma unroll
  for (int j = 0; j < 12; j++) {
    uint64_t w = 0;
#pragma unroll
    for (int m = 0; m < 4; m++) {
      int c = cg * 48 + j * 4 + m;
      float v = (hfv[j * 4 + m] - mu_hf) * rs_hf * ghf[c] + bhf[c];
      w |= (uint64_t)f2b(v) << (16 * m);
    }
    *(uint64_t*)(s_hfL + t_own * P_HFL + cg * 48 + j * 4) = w;
  }
  __syncthreads();  // B2: staging visible to all waves

  // ---- pull this wave's A-fragments into REGISTERS (own 16 rows only) ----
  const int myrow = wv * 16 + l16;
  bf16x8 lfr0 = *(const bf16x8*)(s_lfL + myrow * P_LFL + quad * 8);
  bf16x8 lfr1 = *(const bf16x8*)(s_lfL + myrow * P_LFL + 32 + quad * 8);
  bf16x8 hfr[6];
#pragma unroll
  for (int ks = 0; ks < 6; ks++)
    hfr[ks] = *(const bf16x8*)(s_hfL + myrow * P_HFL + ks * 32 + quad * 8);
  __syncthreads();  // B2b: frags in regs; whole arena reusable

  const unsigned short* wqT = wT;           // [192][64]
  const unsigned short* wkT = wT + 12288;   // [192][192]
  const unsigned short* wvT = wT + 49152;
  const unsigned short* woT = wT + 86016;

  // ---- stage WqT-all (contiguous 16B pieces, no gathers) + rpb bf16 table ----
#pragma unroll
  for (int i = 0; i < 6; i++) {
    int p = i * 256 + tid;            // 1536 pieces (192 rows x 8)
    int n = p >> 3, sub = p & 7;
    *(uint4*)(s_wq + n * P_WQ + sub * 8) = *(const uint4*)(wqT + n * 64 + sub * 8);
  }
  for (int i = tid; i < 225 * NHEAD; i += 256) s_rpb[i] = f2b(rpb[i]);
  __syncthreads();  // B3: WqT + rpb staged

  const int rowbase = wv * 16 + quad * 4;   // C-layout row base for this lane

  // ---- Q for ALL heads upfront; frags via wave-private PW round trip ----
  bf16x8 aq[NHEAD];
#pragma unroll
  for (int h = 0; h < NHEAD; h++) {
#pragma unroll
    for (int nt = 0; nt < 2; nt++) {
      const int n = h * 32 + nt * 16 + l16;
      floatx4 acc = {0.f, 0.f, 0.f, 0.f};
      acc = mfma_bf16(lfr0, *(const bf16x8*)(s_wq + n * P_WQ + quad * 8), acc);
      acc = mfma_bf16(lfr1, *(const bf16x8*)(s_wq + n * P_WQ + 32 + quad * 8), acc);
      const float bqv = bq[n];
#pragma unroll
      for (int r = 0; r < 4; r++)
        s_pw[(quad * 4 + r) * P_PW + nt * 16 + l16] = f2b(acc[r] + bqv);
    }
    aq[h] = *(const bf16x8*)(s_pw + l16 * P_PW + quad * 8);  // same-wave, in-order DS
  }
  __syncthreads();  // B4: all waves done reading WqT region

  // shared staging of the per-head WkT/WvT slices (contiguous in wT; swizzled dst)
  auto stageKV = [&](int h) {
    const unsigned short* sk = wkT + h * 6144;   // 32 rows x 192
    const unsigned short* sv = wvT + h * 6144;
#pragma unroll
    for (int i = 0; i < 3; i++) {
      int p = i * 256 + tid;          // 768 pieces of 16B per matrix
      int nl = p / 24, sub = p - nl * 24;
      *(uint4*)(s_wkv + nl * 192 + swz8(nl, sub * 8)) =
          *(const uint4*)(sk + nl * 192 + sub * 8);
      *(uint4*)(s_wkv + (32 + nl) * 192 + swz8(32 + nl, sub * 8)) =
          *(const uint4*)(sv + nl * 192 + sub * 8);
    }
  };

  stageKV(0);
  __syncthreads();  // S0: KV(0) staged

  floatx4 oa[12];
  const floatx4 zero = {0.f, 0.f, 0.f, 0.f};
#pragma unroll
  for (int ct = 0; ct < 12; ct++) oa[ct] = zero;

#pragma unroll
  for (int h = 0; h < NHEAD; h++) {
    // ---- K_h -> s_k (A from hfr regs; 2 parallel 3-chains halve MFMA latency) ----
#pragma unroll
    for (int nt = 0; nt < 2; nt++) {
      const int n = h * 32 + nt * 16 + l16;
      const int nl = nt * 16 + l16;
      floatx4 a0 = zero, a1 = zero;
#pragma unroll
      for (int ks = 0; ks < 3; ks++) {
        a0 = mfma_bf16(hfr[ks],
            *(const bf16x8*)(s_wkv + nl * 192 + swz8(nl, ks * 32 + quad * 8)), a0);
        a1 = mfma_bf16(hfr[ks + 3],
            *(const bf16x8*)(s_wkv + nl * 192 + swz8(nl, (ks + 3) * 32 + quad * 8)), a1);
      }
      floatx4 acc = a0 + a1;
      const float bkv = bk[n];
#pragma unroll
      for (int r = 0; r < 4; r++)
        s_k[(rowbase + r) * 64 + swz8(rowbase + r, nt * 16 + l16)] = f2b(acc[r] + bkv);
    }
    // ---- V_h -> s_vt (transposed store, swizzled; split chains) ----
#pragma unroll
    for (int nt = 0; nt < 2; nt++) {
      const int n = h * 32 + nt * 16 + l16;
      const int nl = nt * 16 + l16;
      floatx4 a0 = zero, a1 = zero;
#pragma unroll
      for (int ks = 0; ks < 3; ks++) {
        a0 = mfma_bf16(hfr[ks],
            *(const bf16x8*)(s_wkv + (32 + nl) * 192 + swz8(32 + nl, ks * 32 + quad * 8)), a0);
        a1 = mfma_bf16(hfr[ks + 3],
            *(const bf16x8*)(s_wkv + (32 + nl) * 192 + swz8(32 + nl, (ks + 3) * 32 + quad * 8)), a1);
      }
      floatx4 acc = a0 + a1;
      const float bvv = bv[n];
#pragma unroll
      for (int r = 0; r < 4; r++)
        s_vt[nl * 64 + swz8(nl, rowbase + r)] = f2b(acc[r] + bvv);
    }
    __syncthreads();  // A(h): s_k/s_vt visible; WKV slice dead for all waves

    // ---- stage WoT(h) + KV(h+1); loads retire under the attn math ----
#pragma unroll
    for (int i = 0; i < 3; i++) {
      int p = i * 256 + tid;          // 768 pieces: 192 rows x 4
      int n = p >> 2, sub = p & 3;
      *(uint4*)(s_wo + n * 32 + swz4(n, sub * 8)) =
          *(const uint4*)(woT + n * 192 + h * 32 + sub * 8);
    }
    if (h + 1 < NHEAD) stageKV(h + 1);

    // ---- S = Q K^T * scale + rpb (wave owns query rows wv*16..+15) ----
    float sv[4][4];
#pragma unroll
    for (int ct = 0; ct < 4; ct++) {
      const int kr = ct * 16 + l16;
      bf16x8 kb = *(const bf16x8*)(s_k + kr * 64 + swz8(kr, quad * 8));
      floatx4 acc = zero;
      acc = mfma_bf16(aq[h], kb, acc);
#pragma unroll
      for (int r = 0; r < 4; r++) {
        int row = rowbase + r, col = kr;
        int dy = (row >> 3) - (col >> 3) + 7;
        int dx = (row & 7) - (col & 7) + 7;
        sv[ct][r] = acc[r] * 0.17677669529663688f + b2f(s_rpb[(dy * 15 + dx) * NHEAD + h]);
      }
    }
    // ---- softmax over 64 keys, NO max-subtraction: scores bounded (LN inputs,
    // weight scale 0.02 => |S| <~ 1); exp2 cannot overflow, denom >= 64*exp2(-1). ----
#pragma unroll
    for (int r = 0; r < 4; r++) {
      const float L2E = 1.4426950408889634f;
      float e0 = exp2f(sv[0][r] * L2E);
      float e1 = exp2f(sv[1][r] * L2E);
      float e2 = exp2f(sv[2][r] * L2E);
      float e3 = exp2f(sv[3][r] * L2E);
      float s = e0 + e1 + e2 + e3;
      s += __shfl_xor(s, 1);
      s += __shfl_xor(s, 2);
      s += __shfl_xor(s, 4);
      s += __shfl_xor(s, 8);
      float inv = 1.f / s;
      sv[0][r] = e0 * inv; sv[1][r] = e1 * inv; sv[2][r] = e2 * inv; sv[3][r] = e3 * inv;
    }
    // ---- P -> wave-private PW (no cross-wave barrier needed) ----
#pragma unroll
    for (int ct = 0; ct < 4; ct++)
#pragma unroll
      for (int r = 0; r < 4; r++)
        s_pw[(quad * 4 + r) * P_PW + ct * 16 + l16] = f2b(sv[ct][r]);

    // ---- PV (wave-local P round trip; in-order DS) ----
    floatx4 pv0 = zero, pv1 = zero;
#pragma unroll
    for (int ks = 0; ks < 2; ks++) {
      bf16x8 pa = *(const bf16x8*)(s_pw + l16 * P_PW + ks * 32 + quad * 8);
      pv0 = mfma_bf16(pa, *(const bf16x8*)(s_vt + l16 * 64 + swz8(l16, ks * 32 + quad * 8)), pv0);
      pv1 = mfma_bf16(pa, *(const bf16x8*)(s_vt + (16 + l16) * 64 + swz8(16 + l16, ks * 32 + quad * 8)), pv1);
    }
    // stage AO_h into PW cols 0..31 (same-wave DS ops retire in order)
#pragma unroll
    for (int r = 0; r < 4; r++) {
      s_pw[(quad * 4 + r) * P_PW + l16]      = f2b(pv0[r]);
      s_pw[(quad * 4 + r) * P_PW + 16 + l16] = f2b(pv1[r]);
    }
    bf16x8 aoh = *(const bf16x8*)(s_pw + l16 * P_PW + quad * 8);
    __syncthreads();  // A2(h): WoT(h)+KV(h+1) published; s_k/s_vt reads done

    // ---- O += AO_h @ Wo[h*32:+32, :] (B-frags from staged swz4 LDS) ----
#pragma unroll
    for (int ct = 0; ct < 12; ct++) {
      bf16x8 bb = *(const bf16x8*)(s_wo + (ct * 16 + l16) * 32 + swz4(ct * 16 + l16, quad * 8));
      oa[ct] = mfma_bf16(aoh, bb, oa[ct]);
    }
    // next head's K/V writes s_k/s_vt after A2(h): all waves are past A2 ✓
  }
  __syncthreads();  // Bend: all s_wo/s_wkv reads done before epilogue overwrites

  // ---- epilogue: stage O + bo into [64][200] region @0 (own layout) ----
  unsigned short* s_ostg = (unsigned short*)(smem);
#pragma unroll
  for (int ct = 0; ct < 12; ct++) {
    const int col = ct * 16 + l16;
    const float bov = bo[col];
#pragma unroll
    for (int r = 0; r < 4; r++)
      s_ostg[(rowbase + r) * 200 + col] = f2b(oa[ct][r] + bov);
  }
  __syncthreads();  // Bstg: cross-wave gather follows

  // ---- coalesced float4 store; residual re-read from global (L3-warm) ----
#pragma unroll
  for (int k = 0; k < 12; k++) {
    int chunk = k * 256 + tid;       // 3072 chunks of 4 floats = 192ch x 64tok
    int c   = chunk >> 4;
    int sub = chunk & 15;
    int yy  = sub >> 1;
    int x4  = (sub & 1) << 2;
    int t0  = (yy << 3) + x4;
    size_t gidx = ((size_t)(b * CHF + c) * IMG + (h0 + yy)) * IMG + w0 + x4;
    float4 res = *(const float4*)(yhf + gidx);
    float4 v;
    v.x = b2f(s_ostg[(t0 + 0) * 200 + c]) + res.x;
    v.y = b2f(s_ostg[(t0 + 1) * 200 + c]) + res.y;
    v.z = b2f(s_ostg[(t0 + 2) * 200 + c]) + res.z;
    v.w = b2f(s_ostg[(t0 + 3) * 200 + c]) + res.w;
    *(float4*)(out + gidx) = v;
  }
}

extern "C" void kernel_launch(void* const* d_in, const int* in_sizes, int n_in,
                              void* d_out, int out_size, void* d_ws, size_t ws_size,
                              hipStream_t stream) {
  const float* ylf = (const float*)d_in[0];
  const float* yhf = (const float*)d_in[1];
  const float* glf = (const float*)d_in[2];
  const float* blf = (const float*)d_in[3];
  const float* ghf = (const float*)d_in[4];
  const float* bhf = (const float*)d_in[5];
  const float* Wq  = (const float*)d_in[6];
  const float* bq  = (const float*)d_in[7];
  const float* Wk  = (const float*)d_in[8];
  const float* bk  = (const float*)d_in[9];
  const float* Wv  = (const float*)d_in[10];
  const float* bv  = (const float*)d_in[11];
  const float* Wo  = (const float*)d_in[12];
  const float* bo  = (const float*)d_in[13];
  const float* rpb = (const float*)d_in[14];
  unsigned short* wT = (unsigned short*)d_ws;  // 122880 bf16 = 245760 B

  wca_prep<<<480, 256, 0, stream>>>(Wq, Wk, Wv, Wo, wT);
  wca_main<<<4096, 256, 0, stream>>>(ylf, yhf, glf, blf, ghf, bhf,
                                     bq, bk, bv, bo, rpb, wT, (float*)d_out);
}